// Round 5
// baseline (227.108 us; speedup 1.0000x reference)
//
#include <hip/hip_runtime.h>
#include <math.h>

// DigitCaps dynamic routing, MI355X. Round 4: kill the scratch spill.
// u[B=128, R=864, I=4] f32, W[1, J=166, R=864, O=8, I=4] f32 -> v[128,166,8] f32.
//
// Round-3 post-mortem: ext_vector __fp16 array uh[14][4] was spilled wholesale
// to scratch (WRITE_SIZE 303 MB == 224 B/thread == sizeof(uh)); kernel became
// scratch-BW-bound. Fix: store u_hat as plain uint32_t (packed fp16 pairs),
// pack via cvt_pkrtz bitcast, unpack scalar at use sites (compiler emits
// v_fma_mix for (float)half*float+float). Flat int arrays with constant
// indices SROA-promote reliably.
//
// Structure otherwise unchanged: block = 4 waves sharing one j, 4 consecutive
// b; W[j] staged in 4 chunks of 256 routes (32.9 KB LDS, transposed+padded,
// 0 bank conflicts measured); routing logits never stored (b_r = <u_hat, V>,
// V = running sum of v's); no softmax max-pass (shift-invariant, |b_r| small).

#define BB 128
#define JJ 166
#define RR 864
#define OO 8
#define KMAX 14            // ceil(864/64); k=13 has only lanes 0..31 valid
#define RPAD4 257          // LDS row stride in float4 (256 routes + 1 pad)

typedef __fp16 h2v __attribute__((ext_vector_type(2)));

__device__ __forceinline__ uint32_t pack2(float a, float b) {
    return __builtin_bit_cast(uint32_t, __builtin_amdgcn_cvt_pkrtz(a, b));
}
__device__ __forceinline__ float lo_f(uint32_t u) {
    return (float)__builtin_bit_cast(h2v, u).x;
}
__device__ __forceinline__ float hi_f(uint32_t u) {
    return (float)__builtin_bit_cast(h2v, u).y;
}

__device__ __forceinline__ float wave_sum(float v) {
#pragma unroll
    for (int m = 32; m >= 1; m >>= 1) v += __shfl_xor(v, m, 64);
    return v;
}

__global__ __launch_bounds__(256, 3) void digitcaps_kernel(
    const float* __restrict__ u, const float* __restrict__ W,
    float* __restrict__ out) {
    const int tid = threadIdx.x;
    const int lane = tid & 63;
    const int wave = tid >> 6;

    // 32 blocks per j; consecutive blocks share j for L2 locality.
    const int j = blockIdx.x >> 5;
    const int b = ((blockIdx.x & 31) << 2) + wave;

    const float4* __restrict__ u4 = (const float4*)u;  // [B][R]
    const float4* __restrict__ W4 = (const float4*)W;  // [J][R][O]

    __shared__ float4 wlds[OO * RPAD4];  // 32,896 B

    uint32_t uh[KMAX][4];  // u_hat packed fp16 pairs; plain ints -> SROA-safe

    // ---- stage W[j] in 4 chunks of 256 r; compute u_hat into packed regs ----
#pragma unroll
    for (int c = 0; c < 4; ++c) {
        __syncthreads();  // protect LDS reuse across chunks
        const int base_r = c << 8;                      // 0,256,512,768
        const int gbase = j * (RR * OO) + base_r * OO;  // float4 index
        const int iters = (c < 3) ? 8 : 3;              // (256|96)*8/256
#pragma unroll
        for (int i = 0; i < iters; ++i) {
            const int e = tid + (i << 8);
            const float4 w = W4[gbase + e];
            wlds[(e & 7) * RPAD4 + (e >> 3)] = w;  // transposed: [o][r_local]
        }
        __syncthreads();

        const int kk = (c < 3) ? 4 : 2;
#pragma unroll
        for (int kl = 0; kl < kk; ++kl) {
            const int k = (c << 2) + kl;
            const int rl = (kl << 6) + lane;
            const int r = base_r + rl;
            if (r < RR) {  // only k==13, lane>=32 fails
                const float4 uu = u4[b * RR + r];
                float d[OO];
#pragma unroll
                for (int o = 0; o < OO; ++o) {
                    const float4 ww = wlds[o * RPAD4 + rl];
                    d[o] = ww.x * uu.x + ww.y * uu.y + ww.z * uu.z + ww.w * uu.w;
                }
#pragma unroll
                for (int o2 = 0; o2 < 4; ++o2)
                    uh[k][o2] = pack2(d[2 * o2], d[2 * o2 + 1]);
            } else {
#pragma unroll
                for (int o2 = 0; o2 < 4; ++o2) uh[k][o2] = 0u;
            }
        }
    }

    float V[OO];  // running sum of past v's (b_r = <uhat_r, V>)
    float v[OO];

    // ---- iteration 0: b=0 -> c uniform = 1/R ----
    {
        float acc[OO];
#pragma unroll
        for (int o = 0; o < OO; ++o) acc[o] = 0.0f;
#pragma unroll
        for (int k = 0; k < KMAX; ++k)
#pragma unroll
            for (int o2 = 0; o2 < 4; ++o2) {
                acc[2 * o2]     += lo_f(uh[k][o2]);
                acc[2 * o2 + 1] += hi_f(uh[k][o2]);
            }

        float s[OO];
#pragma unroll
        for (int o = 0; o < OO; ++o)
            s[o] = wave_sum(acc[o]) * (1.0f / (float)RR);

        float n2 = 0.0f;
#pragma unroll
        for (int o = 0; o < OO; ++o) n2 += s[o] * s[o];
        const float scale = sqrtf(n2) / (1.0f + n2);
#pragma unroll
        for (int o = 0; o < OO; ++o) { v[o] = s[o] * scale; V[o] = v[o]; }
    }

    // ---- iterations 1 and 2 ----
#pragma unroll
    for (int it = 1; it < 3; ++it) {
        float zp = 0.0f;
        float sp[OO];
#pragma unroll
        for (int o = 0; o < OO; ++o) sp[o] = 0.0f;

#pragma unroll
        for (int k = 0; k < KMAX; ++k) {
            float uf[OO];
#pragma unroll
            for (int o2 = 0; o2 < 4; ++o2) {
                uf[2 * o2]     = lo_f(uh[k][o2]);
                uf[2 * o2 + 1] = hi_f(uh[k][o2]);
            }
            float br = 0.0f;
#pragma unroll
            for (int o = 0; o < OO; ++o) br = fmaf(uf[o], V[o], br);
            // mask invalid routes (k==13, lane>=32): exp(0)=1 would pollute Z
            const float e = (k < KMAX - 1 || lane < 32) ? __expf(br) : 0.0f;
            zp += e;
#pragma unroll
            for (int o = 0; o < OO; ++o) sp[o] = fmaf(e, uf[o], sp[o]);
        }
        const float invZ = 1.0f / wave_sum(zp);

        float s[OO];
#pragma unroll
        for (int o = 0; o < OO; ++o) s[o] = wave_sum(sp[o]) * invZ;

        float n2 = 0.0f;
#pragma unroll
        for (int o = 0; o < OO; ++o) n2 += s[o] * s[o];
        const float scale = sqrtf(n2) / (1.0f + n2);
#pragma unroll
        for (int o = 0; o < OO; ++o) v[o] = s[o] * scale;

        if (it < 2) {
#pragma unroll
            for (int o = 0; o < OO; ++o) V[o] += v[o];
        }
    }

    // ---- write out[b][j][o]; v replicated across lanes after butterflies ----
    float outv = 0.0f;
#pragma unroll
    for (int o = 0; o < OO; ++o)
        if (lane == o) outv = v[o];
    if (lane < OO) out[(b * JJ + j) * OO + lane] = outv;
}

extern "C" void kernel_launch(void* const* d_in, const int* in_sizes, int n_in,
                              void* d_out, int out_size, void* d_ws, size_t ws_size,
                              hipStream_t stream) {
    const float* u = (const float*)d_in[0];  // [128, 864, 4]
    const float* W = (const float*)d_in[1];  // [1, 166, 864, 8, 4]
    float* out = (float*)d_out;              // [128, 166, 8]

    const int grid = JJ * (BB / 4);  // 5312 blocks, 4 waves each
    digitcaps_kernel<<<grid, 256, 0, stream>>>(u, W, out);
}

// Round 6
// 162.292 us; speedup vs baseline: 1.3994x; 1.3994x over previous
//
#include <hip/hip_runtime.h>
#include <math.h>

// DigitCaps dynamic routing, MI355X. Round 5: force chunk-loop unroll (macro),
// killing the scratch-resident u_hat array.
// u[B=128, R=864, I=4] f32, W[1, J=166, R=864, O=8, I=4] f32 -> v[128,166,8] f32.
//
// Round-4 post-mortem: WRITE_SIZE 362 MB / 266 B per thread == the packed
// u_hat array spilled to scratch. Root cause: the outer 4-chunk loop (with
// two __syncthreads in the body) was NOT fully unrolled, so uh[(c<<2)+kl] had
// a runtime index -> SROA failed -> array in scratch. Fix: expand chunks via
// macro with LITERAL chunk ids; all uh indices become compile-time constants.
//
// Structure: block = 4 waves sharing one j, 4 consecutive b. W[j] staged in
// 4 chunks of 256 routes (32.9 KB LDS, transposed+padded, 0 bank conflicts
// measured). u_hat packed fp16 pairs in uint32 regs (56 VGPRs), fp32
// accumulation everywhere. Routing logits never stored: b_r = <u_hat, V>,
// V = running sum of v's. No softmax max-pass (shift-invariant, |b_r| small).

#define BB 128
#define JJ 166
#define RR 864
#define OO 8
#define KMAX 14            // ceil(864/64); k=13 has only lanes 0..31 valid
#define RPAD4 257          // LDS row stride in float4 (256 routes + 1 pad)

typedef __fp16 h2v __attribute__((ext_vector_type(2)));

__device__ __forceinline__ uint32_t pack2(float a, float b) {
    return __builtin_bit_cast(uint32_t, __builtin_amdgcn_cvt_pkrtz(a, b));
}
__device__ __forceinline__ float lo_f(uint32_t u) {
    return (float)__builtin_bit_cast(h2v, u).x;
}
__device__ __forceinline__ float hi_f(uint32_t u) {
    return (float)__builtin_bit_cast(h2v, u).y;
}

__device__ __forceinline__ float wave_sum(float v) {
#pragma unroll
    for (int m = 32; m >= 1; m >>= 1) v += __shfl_xor(v, m, 64);
    return v;
}

__global__ __launch_bounds__(256) void digitcaps_kernel(
    const float* __restrict__ u, const float* __restrict__ W,
    float* __restrict__ out) {
    const int tid = threadIdx.x;
    const int lane = tid & 63;
    const int wave = tid >> 6;

    // 32 blocks per j; consecutive blocks share j for L2 locality.
    const int j = blockIdx.x >> 5;
    const int b = ((blockIdx.x & 31) << 2) + wave;

    const float4* __restrict__ u4 = (const float4*)u;  // [B][R]
    const float4* __restrict__ W4 = (const float4*)W;  // [J][R][O]

    __shared__ float4 wlds[OO * RPAD4];  // 32,896 B

    uint32_t uh[KMAX][4];  // u_hat packed fp16 pairs; constant-indexed only

    // ---- stage W[j] chunk CC (256 routes); compute u_hat for those k ----
    // CC is a LITERAL so every uh index is a compile-time constant.
#define CHUNK(CC, ITERS, KK)                                                   \
    {                                                                          \
        __syncthreads();                                                       \
        const int gbase = j * (RR * OO) + (CC * 256) * OO;                     \
        _Pragma("unroll")                                                      \
        for (int i = 0; i < (ITERS); ++i) {                                    \
            const int e = tid + (i << 8);                                      \
            const float4 w = W4[gbase + e];                                    \
            wlds[(e & 7) * RPAD4 + (e >> 3)] = w; /* transposed [o][r_local] */\
        }                                                                      \
        __syncthreads();                                                       \
        _Pragma("unroll")                                                      \
        for (int kl = 0; kl < (KK); ++kl) {                                    \
            const int rl = (kl << 6) + lane;                                   \
            const int r = (CC * 256) + rl;                                     \
            if (r < RR) { /* only k==13, lane>=32 fails */                     \
                const float4 uu = u4[b * RR + r];                              \
                float d[OO];                                                   \
                _Pragma("unroll")                                              \
                for (int o = 0; o < OO; ++o) {                                 \
                    const float4 ww = wlds[o * RPAD4 + rl];                    \
                    d[o] = ww.x * uu.x + ww.y * uu.y + ww.z * uu.z +           \
                           ww.w * uu.w;                                        \
                }                                                              \
                _Pragma("unroll")                                              \
                for (int o2 = 0; o2 < 4; ++o2)                                 \
                    uh[(CC) * 4 + kl][o2] = pack2(d[2 * o2], d[2 * o2 + 1]);   \
            } else {                                                           \
                _Pragma("unroll")                                              \
                for (int o2 = 0; o2 < 4; ++o2) uh[(CC) * 4 + kl][o2] = 0u;     \
            }                                                                  \
        }                                                                      \
    }

    CHUNK(0, 8, 4)
    CHUNK(1, 8, 4)
    CHUNK(2, 8, 4)
    CHUNK(3, 3, 2)
#undef CHUNK

    float V[OO];  // running sum of past v's (b_r = <uhat_r, V>)
    float v[OO];

    // ---- iteration 0: b=0 -> c uniform = 1/R ----
    {
        float acc[OO];
#pragma unroll
        for (int o = 0; o < OO; ++o) acc[o] = 0.0f;
#pragma unroll
        for (int k = 0; k < KMAX; ++k)
#pragma unroll
            for (int o2 = 0; o2 < 4; ++o2) {
                acc[2 * o2]     += lo_f(uh[k][o2]);
                acc[2 * o2 + 1] += hi_f(uh[k][o2]);
            }

        float s[OO];
#pragma unroll
        for (int o = 0; o < OO; ++o)
            s[o] = wave_sum(acc[o]) * (1.0f / (float)RR);

        float n2 = 0.0f;
#pragma unroll
        for (int o = 0; o < OO; ++o) n2 += s[o] * s[o];
        const float scale = sqrtf(n2) / (1.0f + n2);
#pragma unroll
        for (int o = 0; o < OO; ++o) { v[o] = s[o] * scale; V[o] = v[o]; }
    }

    // ---- iterations 1 and 2 ----
#pragma unroll
    for (int it = 1; it < 3; ++it) {
        float zp = 0.0f;
        float sp[OO];
#pragma unroll
        for (int o = 0; o < OO; ++o) sp[o] = 0.0f;

#pragma unroll
        for (int k = 0; k < KMAX; ++k) {
            float uf[OO];
#pragma unroll
            for (int o2 = 0; o2 < 4; ++o2) {
                uf[2 * o2]     = lo_f(uh[k][o2]);
                uf[2 * o2 + 1] = hi_f(uh[k][o2]);
            }
            float br = 0.0f;
#pragma unroll
            for (int o = 0; o < OO; ++o) br = fmaf(uf[o], V[o], br);
            // mask invalid routes (k==13, lane>=32): exp(0)=1 would pollute Z
            const float e = (k < KMAX - 1 || lane < 32) ? __expf(br) : 0.0f;
            zp += e;
#pragma unroll
            for (int o = 0; o < OO; ++o) sp[o] = fmaf(e, uf[o], sp[o]);
        }
        const float invZ = 1.0f / wave_sum(zp);

        float s[OO];
#pragma unroll
        for (int o = 0; o < OO; ++o) s[o] = wave_sum(sp[o]) * invZ;

        float n2 = 0.0f;
#pragma unroll
        for (int o = 0; o < OO; ++o) n2 += s[o] * s[o];
        const float scale = sqrtf(n2) / (1.0f + n2);
#pragma unroll
        for (int o = 0; o < OO; ++o) v[o] = s[o] * scale;

        if (it < 2) {
#pragma unroll
            for (int o = 0; o < OO; ++o) V[o] += v[o];
        }
    }

    // ---- write out[b][j][o]; v replicated across lanes after butterflies ----
    float outv = 0.0f;
#pragma unroll
    for (int o = 0; o < OO; ++o)
        if (lane == o) outv = v[o];
    if (lane < OO) out[(b * JJ + j) * OO + lane] = outv;
}

extern "C" void kernel_launch(void* const* d_in, const int* in_sizes, int n_in,
                              void* d_out, int out_size, void* d_ws, size_t ws_size,
                              hipStream_t stream) {
    const float* u = (const float*)d_in[0];  // [128, 864, 4]
    const float* W = (const float*)d_in[1];  // [1, 166, 864, 8, 4]
    float* out = (float*)d_out;              // [128, 166, 8]

    const int grid = JJ * (BB / 4);  // 5312 blocks, 4 waves each
    digitcaps_kernel<<<grid, 256, 0, stream>>>(u, W, out);
}

// Round 7
// 155.919 us; speedup vs baseline: 1.4566x; 1.0409x over previous
//
#include <hip/hip_runtime.h>
#include <math.h>

// DigitCaps dynamic routing, MI355X. Round 6: fp16 W staging + LDS double
// buffering + dot2 u_hat compute.
// u[B=128, R=864, I=4] f32, W[1, J=166, R=864, O=8, I=4] f32 -> v[128,166,8] f32.
//
// Round-5 post-mortem: spill gone, 112 us kernel, VALUBusy 51% -> half the
// time is stall (phase-locked staging barriers: vmcnt(0)+s_barrier per chunk
// not overlapped since all blocks stage in lockstep). Round 6:
//  (1) W staged as packed fp16 pairs: LDS chunk 16.4 KB -> two buffers fit in
//      the old 33 KB footprint; u_hat via v_dot2_f32_f16 (2 inst per (k,o)
//      instead of 4 FMA).
//  (2) Double-buffered staging: chunk c+1's global loads issued before chunk
//      c's compute; one barrier per chunk; loads fly during compute.
//  (3) iter-0 route-sum via v_pk_add_f16 on packed u_hat.
// All u_hat indices remain compile-time constants (macro with literal chunk
// ids) — the round-4 spill lesson. __launch_bounds__(256,4) caps VGPR at 128
// (4 waves/SIMD); WRITE_SIZE would expose any respill.

#define BB 128
#define JJ 166
#define RR 864
#define OO 8
#define KMAX 14            // ceil(864/64); k=13 has only lanes 0..31 valid
#define RPAD2 257          // LDS row stride in uint2 (256 routes + 1 pad)

typedef __fp16 h2v __attribute__((ext_vector_type(2)));

__device__ __forceinline__ uint32_t pack2(float a, float b) {
    return __builtin_bit_cast(uint32_t, __builtin_amdgcn_cvt_pkrtz(a, b));
}
__device__ __forceinline__ h2v bc_h2(uint32_t u) {
    return __builtin_bit_cast(h2v, u);
}
__device__ __forceinline__ float lo_f(uint32_t u) {
    return (float)__builtin_bit_cast(h2v, u).x;
}
__device__ __forceinline__ float hi_f(uint32_t u) {
    return (float)__builtin_bit_cast(h2v, u).y;
}

__device__ __forceinline__ float wave_sum(float v) {
#pragma unroll
    for (int m = 32; m >= 1; m >>= 1) v += __shfl_xor(v, m, 64);
    return v;
}

__global__ __launch_bounds__(256, 4) void digitcaps_kernel(
    const float* __restrict__ u, const float* __restrict__ W,
    float* __restrict__ out) {
    const int tid = threadIdx.x;
    const int lane = tid & 63;
    const int wave = tid >> 6;

    // 32 blocks per j; consecutive blocks share j for L2 locality.
    const int j = blockIdx.x >> 5;
    const int b = ((blockIdx.x & 31) << 2) + wave;

    const float4* __restrict__ u4 = (const float4*)u;  // [B][R]
    const float4* __restrict__ W4 = (const float4*)W;  // [J][R][O]

    // two buffers, each [o][r_local] of uint2 (4 fp16 = W[j,r,o,:])
    __shared__ uint2 wlds[2][OO * RPAD2];  // 2 x 16,448 B = 32,896 B

    uint32_t uh[KMAX][4];  // u_hat packed fp16 pairs; constant-indexed only

    float4 wA[8], wB[8];   // staging bursts (alternating)

    // ---- issue global loads for chunk CC into burst array WREG ----
#define ISSUE(CC, ITERS, WREG)                                                 \
    {                                                                          \
        const int gbase = j * (RR * OO) + (CC * 256) * OO;                     \
        _Pragma("unroll")                                                      \
        for (int i = 0; i < (ITERS); ++i) WREG[i] = W4[gbase + tid + (i << 8)];\
    }

    // ---- pack+write burst WREG into LDS buffer BUF ----
#define STAGE(BUF, ITERS, WREG)                                                \
    {                                                                          \
        _Pragma("unroll")                                                      \
        for (int i = 0; i < (ITERS); ++i) {                                    \
            const int e = tid + (i << 8);                                      \
            wlds[BUF][(e & 7) * RPAD2 + (e >> 3)] =                            \
                make_uint2(pack2(WREG[i].x, WREG[i].y),                        \
                           pack2(WREG[i].z, WREG[i].w));                       \
        }                                                                      \
    }

    // ---- compute u_hat for chunk CC (KK k-slots) from LDS buffer BUF ----
#define COMPUTE(CC, BUF, KK)                                                   \
    {                                                                          \
        _Pragma("unroll")                                                      \
        for (int kl = 0; kl < (KK); ++kl) {                                    \
            const int rl = (kl << 6) + lane;                                   \
            const int r = (CC * 256) + rl;                                     \
            if (r < RR) { /* only k==13, lane>=32 fails */                     \
                const float4 uu = u4[b * RR + r];                              \
                const uint32_t up0 = pack2(uu.x, uu.y);                        \
                const uint32_t up1 = pack2(uu.z, uu.w);                        \
                float d[OO];                                                   \
                _Pragma("unroll")                                              \
                for (int o = 0; o < OO; ++o) {                                 \
                    const uint2 ww = wlds[BUF][o * RPAD2 + rl];                \
                    float t = __builtin_amdgcn_fdot2(bc_h2(ww.x), bc_h2(up0),  \
                                                     0.0f, false);             \
                    d[o] = __builtin_amdgcn_fdot2(bc_h2(ww.y), bc_h2(up1), t,  \
                                                  false);                      \
                }                                                              \
                _Pragma("unroll")                                              \
                for (int o2 = 0; o2 < 4; ++o2)                                 \
                    uh[(CC) * 4 + kl][o2] = pack2(d[2 * o2], d[2 * o2 + 1]);   \
            } else {                                                           \
                _Pragma("unroll")                                              \
                for (int o2 = 0; o2 < 4; ++o2) uh[(CC) * 4 + kl][o2] = 0u;     \
            }                                                                  \
        }                                                                      \
    }

    // Pipeline: one barrier per chunk; next chunk's loads in flight during
    // compute. Buffer reuse is safe: compute(c) precedes the barrier after
    // write(c+1), so by the time any wave writes buffer c%2 again (chunk c+2),
    // all waves have passed that barrier, hence finished compute(c).
    ISSUE(0, 8, wA)
    STAGE(0, 8, wA)
    __syncthreads();
    ISSUE(1, 8, wB)
    COMPUTE(0, 0, 4)
    STAGE(1, 8, wB)
    __syncthreads();
    ISSUE(2, 8, wA)
    COMPUTE(1, 1, 4)
    STAGE(0, 8, wA)
    __syncthreads();
    ISSUE(3, 3, wB)
    COMPUTE(2, 0, 4)
    STAGE(1, 3, wB)
    __syncthreads();
    COMPUTE(3, 1, 2)
#undef ISSUE
#undef STAGE
#undef COMPUTE

    float V[OO];  // running sum of past v's (b_r = <uhat_r, V>)
    float v[OO];

    // ---- iteration 0: b=0 -> c uniform = 1/R (packed fp16 partial sums) ----
    {
        h2v accp[4];
#pragma unroll
        for (int o2 = 0; o2 < 4; ++o2) accp[o2] = bc_h2(uh[0][o2]);
#pragma unroll
        for (int k = 1; k < KMAX; ++k)
#pragma unroll
            for (int o2 = 0; o2 < 4; ++o2) accp[o2] += bc_h2(uh[k][o2]);

        float s[OO];
#pragma unroll
        for (int o2 = 0; o2 < 4; ++o2) {
            s[2 * o2]     = wave_sum((float)accp[o2].x) * (1.0f / (float)RR);
            s[2 * o2 + 1] = wave_sum((float)accp[o2].y) * (1.0f / (float)RR);
        }
        float n2 = 0.0f;
#pragma unroll
        for (int o = 0; o < OO; ++o) n2 += s[o] * s[o];
        const float scale = sqrtf(n2) / (1.0f + n2);
#pragma unroll
        for (int o = 0; o < OO; ++o) { v[o] = s[o] * scale; V[o] = v[o]; }
    }

    // ---- iterations 1 and 2 ----
#pragma unroll
    for (int it = 1; it < 3; ++it) {
        float zp = 0.0f;
        float sp[OO];
#pragma unroll
        for (int o = 0; o < OO; ++o) sp[o] = 0.0f;

#pragma unroll
        for (int k = 0; k < KMAX; ++k) {
            float br = 0.0f;
#pragma unroll
            for (int o2 = 0; o2 < 4; ++o2) {
                br = fmaf(lo_f(uh[k][o2]), V[2 * o2], br);
                br = fmaf(hi_f(uh[k][o2]), V[2 * o2 + 1], br);
            }
            // mask invalid routes (k==13, lane>=32): exp(0)=1 would pollute Z
            const float e = (k < KMAX - 1 || lane < 32) ? __expf(br) : 0.0f;
            zp += e;
#pragma unroll
            for (int o2 = 0; o2 < 4; ++o2) {
                sp[2 * o2]     = fmaf(e, lo_f(uh[k][o2]), sp[2 * o2]);
                sp[2 * o2 + 1] = fmaf(e, hi_f(uh[k][o2]), sp[2 * o2 + 1]);
            }
        }
        const float invZ = 1.0f / wave_sum(zp);

        float s[OO];
#pragma unroll
        for (int o = 0; o < OO; ++o) s[o] = wave_sum(sp[o]) * invZ;

        float n2 = 0.0f;
#pragma unroll
        for (int o = 0; o < OO; ++o) n2 += s[o] * s[o];
        const float scale = sqrtf(n2) / (1.0f + n2);
#pragma unroll
        for (int o = 0; o < OO; ++o) v[o] = s[o] * scale;

        if (it < 2) {
#pragma unroll
            for (int o = 0; o < OO; ++o) V[o] += v[o];
        }
    }

    // ---- write out[b][j][o]; v replicated across lanes after butterflies ----
    float outv = 0.0f;
#pragma unroll
    for (int o = 0; o < OO; ++o)
        if (lane == o) outv = v[o];
    if (lane < OO) out[(b * JJ + j) * OO + lane] = outv;
}

extern "C" void kernel_launch(void* const* d_in, const int* in_sizes, int n_in,
                              void* d_out, int out_size, void* d_ws, size_t ws_size,
                              hipStream_t stream) {
    const float* u = (const float*)d_in[0];  // [128, 864, 4]
    const float* W = (const float*)d_in[1];  // [1, 166, 864, 8, 4]
    float* out = (float*)d_out;              // [128, 166, 8]

    const int grid = JJ * (BB / 4);  // 5312 blocks, 4 waves each
    digitcaps_kernel<<<grid, 256, 0, stream>>>(u, W, out);
}

// Round 8
// 142.867 us; speedup vs baseline: 1.5896x; 1.0914x over previous
//
#include <hip/hip_runtime.h>
#include <math.h>

// DigitCaps dynamic routing, MI355X. Round 7: double-buffered fp16 pipeline
// WITHOUT burst register arrays (round-6 spill fix).
// u[B=128, R=864, I=4] f32, W[1, J=166, R=864, O=8, I=4] f32 -> v[128,166,8] f32.
//
// Round-6 post-mortem: wA[8]/wB[8] burst arrays (64 VGPRs) + launch_bounds
// (256,4) cap forced a 104 B/thread spill (WRITE_SIZE 138 MB). Fix: merged
// load->pack->ds_write staging loop (transient regs only, compiler keeps
// loads in flight via fine-grained vmcnt — verified by round-5 behavior),
// no min-waves clamp (LDS 33 KB already caps at 4 blocks/CU).
// Pipeline per phase: stage(chunk c+1 -> buf (c+1)&1) issued first, then
// compute(chunk c from buf c&1); one barrier per phase. Buffer-reuse safety:
// writes to buf X in phase p are separated by a barrier from phase p-1's
// compute reads of buf X.
// Routing: u_hat packed fp16 pairs in uint32 regs (constant-indexed macro
// expansion — round-4 lesson); logits b_r = <u_hat, V> via v_dot2_f32_f16
// against packed V; V = running sum of v's; no softmax max-pass
// (shift-invariant, |b_r| small, fp32 exp).

#define BB 128
#define JJ 166
#define RR 864
#define OO 8
#define KMAX 14            // ceil(864/64); k=13 has only lanes 0..31 valid
#define RPAD2 257          // LDS row stride in uint2 (256 routes + 1 pad)

typedef __fp16 h2v __attribute__((ext_vector_type(2)));

__device__ __forceinline__ uint32_t pack2(float a, float b) {
    return __builtin_bit_cast(uint32_t, __builtin_amdgcn_cvt_pkrtz(a, b));
}
__device__ __forceinline__ h2v bc_h2(uint32_t u) {
    return __builtin_bit_cast(h2v, u);
}
__device__ __forceinline__ float lo_f(uint32_t u) {
    return (float)__builtin_bit_cast(h2v, u).x;
}
__device__ __forceinline__ float hi_f(uint32_t u) {
    return (float)__builtin_bit_cast(h2v, u).y;
}

__device__ __forceinline__ float wave_sum(float v) {
#pragma unroll
    for (int m = 32; m >= 1; m >>= 1) v += __shfl_xor(v, m, 64);
    return v;
}

__global__ __launch_bounds__(256) void digitcaps_kernel(
    const float* __restrict__ u, const float* __restrict__ W,
    float* __restrict__ out) {
    const int tid = threadIdx.x;
    const int lane = tid & 63;
    const int wave = tid >> 6;

    // 32 blocks per j; consecutive blocks share j for L2 locality.
    const int j = blockIdx.x >> 5;
    const int b = ((blockIdx.x & 31) << 2) + wave;

    const float4* __restrict__ u4 = (const float4*)u;  // [B][R]
    const float4* __restrict__ W4 = (const float4*)W;  // [J][R][O]

    // two buffers, each [o][r_local] of uint2 (4 fp16 = W[j,r,o,:])
    __shared__ uint2 wlds[2][OO * RPAD2];  // 2 x 16,448 B = 32,896 B

    uint32_t uh[KMAX][4];  // u_hat packed fp16 pairs; constant-indexed only

    // ---- stage chunk CC into LDS buffer BUF: load -> pack -> write ----
#define STAGE(CC, BUF, ITERS)                                                  \
    {                                                                          \
        const int gbase = j * (RR * OO) + (CC * 256) * OO;                     \
        _Pragma("unroll")                                                      \
        for (int i = 0; i < (ITERS); ++i) {                                    \
            const int e = tid + (i << 8);                                      \
            const float4 w = W4[gbase + e];                                    \
            wlds[BUF][(e & 7) * RPAD2 + (e >> 3)] =                            \
                make_uint2(pack2(w.x, w.y), pack2(w.z, w.w));                  \
        }                                                                      \
    }

    // ---- compute u_hat for chunk CC (KK k-slots) from LDS buffer BUF ----
#define COMPUTE(CC, BUF, KK)                                                   \
    {                                                                          \
        _Pragma("unroll")                                                      \
        for (int kl = 0; kl < (KK); ++kl) {                                    \
            const int rl = (kl << 6) + lane;                                   \
            const int r = (CC * 256) + rl;                                     \
            if (r < RR) { /* only k==13, lane>=32 fails */                     \
                const float4 uu = u4[b * RR + r];                              \
                const uint32_t up0 = pack2(uu.x, uu.y);                        \
                const uint32_t up1 = pack2(uu.z, uu.w);                        \
                float d[OO];                                                   \
                _Pragma("unroll")                                              \
                for (int o = 0; o < OO; ++o) {                                 \
                    const uint2 ww = wlds[BUF][o * RPAD2 + rl];                \
                    float t = __builtin_amdgcn_fdot2(bc_h2(ww.x), bc_h2(up0),  \
                                                     0.0f, false);             \
                    d[o] = __builtin_amdgcn_fdot2(bc_h2(ww.y), bc_h2(up1), t,  \
                                                  false);                      \
                }                                                              \
                _Pragma("unroll")                                              \
                for (int o2 = 0; o2 < 4; ++o2)                                 \
                    uh[(CC) * 4 + kl][o2] = pack2(d[2 * o2], d[2 * o2 + 1]);   \
            } else {                                                           \
                _Pragma("unroll")                                              \
                for (int o2 = 0; o2 < 4; ++o2) uh[(CC) * 4 + kl][o2] = 0u;     \
            }                                                                  \
        }                                                                      \
    }

    STAGE(0, 0, 8)
    __syncthreads();
    STAGE(1, 1, 8)        // loads fly while computing chunk 0
    COMPUTE(0, 0, 4)
    __syncthreads();
    STAGE(2, 0, 8)
    COMPUTE(1, 1, 4)
    __syncthreads();
    STAGE(3, 1, 3)
    COMPUTE(2, 0, 4)
    __syncthreads();
    COMPUTE(3, 1, 2)
#undef STAGE
#undef COMPUTE

    float V[OO];  // running sum of past v's (b_r = <uhat_r, V>)
    float v[OO];

    // ---- iteration 0: b=0 -> c uniform = 1/R (packed fp16 partial sums) ----
    {
        h2v accp[4];
#pragma unroll
        for (int o2 = 0; o2 < 4; ++o2) accp[o2] = bc_h2(uh[0][o2]);
#pragma unroll
        for (int k = 1; k < KMAX; ++k)
#pragma unroll
            for (int o2 = 0; o2 < 4; ++o2) accp[o2] += bc_h2(uh[k][o2]);

        float s[OO];
#pragma unroll
        for (int o2 = 0; o2 < 4; ++o2) {
            s[2 * o2]     = wave_sum((float)accp[o2].x) * (1.0f / (float)RR);
            s[2 * o2 + 1] = wave_sum((float)accp[o2].y) * (1.0f / (float)RR);
        }
        float n2 = 0.0f;
#pragma unroll
        for (int o = 0; o < OO; ++o) n2 += s[o] * s[o];
        const float scale = sqrtf(n2) / (1.0f + n2);
#pragma unroll
        for (int o = 0; o < OO; ++o) { v[o] = s[o] * scale; V[o] = v[o]; }
    }

    // ---- iterations 1 and 2 ----
#pragma unroll
    for (int it = 1; it < 3; ++it) {
        // pack V once per iteration for dot2 logits
        uint32_t Vp[4];
#pragma unroll
        for (int o2 = 0; o2 < 4; ++o2)
            Vp[o2] = pack2(V[2 * o2], V[2 * o2 + 1]);

        float zp = 0.0f;
        float sp[OO];
#pragma unroll
        for (int o = 0; o < OO; ++o) sp[o] = 0.0f;

#pragma unroll
        for (int k = 0; k < KMAX; ++k) {
            float br = 0.0f;
#pragma unroll
            for (int o2 = 0; o2 < 4; ++o2)
                br = __builtin_amdgcn_fdot2(bc_h2(uh[k][o2]), bc_h2(Vp[o2]),
                                            br, false);
            // mask invalid routes (k==13, lane>=32): exp(0)=1 would pollute Z
            const float e = (k < KMAX - 1 || lane < 32) ? __expf(br) : 0.0f;
            zp += e;
#pragma unroll
            for (int o2 = 0; o2 < 4; ++o2) {
                sp[2 * o2]     = fmaf(e, lo_f(uh[k][o2]), sp[2 * o2]);
                sp[2 * o2 + 1] = fmaf(e, hi_f(uh[k][o2]), sp[2 * o2 + 1]);
            }
        }
        const float invZ = 1.0f / wave_sum(zp);

        float s[OO];
#pragma unroll
        for (int o = 0; o < OO; ++o) s[o] = wave_sum(sp[o]) * invZ;

        float n2 = 0.0f;
#pragma unroll
        for (int o = 0; o < OO; ++o) n2 += s[o] * s[o];
        const float scale = sqrtf(n2) / (1.0f + n2);
#pragma unroll
        for (int o = 0; o < OO; ++o) v[o] = s[o] * scale;

        if (it < 2) {
#pragma unroll
            for (int o = 0; o < OO; ++o) V[o] += v[o];
        }
    }

    // ---- write out[b][j][o]; v replicated across lanes after butterflies ----
    float outv = 0.0f;
#pragma unroll
    for (int o = 0; o < OO; ++o)
        if (lane == o) outv = v[o];
    if (lane < OO) out[(b * JJ + j) * OO + lane] = outv;
}

extern "C" void kernel_launch(void* const* d_in, const int* in_sizes, int n_in,
                              void* d_out, int out_size, void* d_ws, size_t ws_size,
                              hipStream_t stream) {
    const float* u = (const float*)d_in[0];  // [128, 864, 4]
    const float* W = (const float*)d_in[1];  // [1, 166, 864, 8, 4]
    float* out = (float*)d_out;              // [128, 166, 8]

    const int grid = JJ * (BB / 4);  // 5312 blocks, 4 waves each
    digitcaps_kernel<<<grid, 256, 0, stream>>>(u, W, out);
}